// Round 11
// baseline (2189.636 us; speedup 1.0000x reference)
//
#include <hip/hip_runtime.h>
#include <cmath>

// ---------------- problem constants ----------------
#define Bb 4
#define Tt 1024
#define DIN 560
#define Dd 512
#define FFd 2048
#define Ll 6
#define BT (Bb * Tt)          // 4096 rows
#define QKV_N (3 * Dd)        // 1536

typedef unsigned short u16;
typedef unsigned int u32;
typedef __attribute__((ext_vector_type(8))) short short8;
typedef __attribute__((ext_vector_type(4))) float f32x4;

static __device__ __forceinline__ u16 f2bf(float f) {          // RNE fp32->bf16
    u32 u = __float_as_uint(f);
    return (u16)((u + 0x7fffu + ((u >> 16) & 1u)) >> 16);
}
static __device__ __forceinline__ float bf2f(u16 h) { return __uint_as_float((u32)h << 16); }

static __device__ __forceinline__ f32x4 MFMA(short8 a, short8 b, f32x4 c) {
    return __builtin_amdgcn_mfma_f32_16x16x32_bf16(a, b, c, 0, 0, 0);
}

static __device__ __forceinline__ void gload16(const u16* g, u16* l) {
    __builtin_amdgcn_global_load_lds(
        (const __attribute__((address_space(1))) void*)g,
        (__attribute__((address_space(3))) void*)l, 16, 0, 0);
}

// ---------------- 1. preprocess: x*sqrt(D) + pos_encode ----------------
__global__ __launch_bounds__(256) void prep_kernel(const float* __restrict__ x,
                                                   float* __restrict__ out) {
    int idx = blockIdx.x * 256 + threadIdx.x;       // over BT*DIN, exact
    int d = idx % DIN;
    int bt = idx / DIN;
    int t = bt & (Tt - 1);
    const float log_inc = 9.210340371976184f / 279.0f;   // ln(10000)/(half-1)
    int i = (d < 280) ? d : d - 280;
    float ang = (float)(t + 1) * expf(-(float)i * log_inc);
    float pe = (d < 280) ? sinf(ang) : cosf(ang);
    out[idx] = x[idx] * 22.627416997969522f + pe;        // sqrt(512)
}

// ---------------- 2a. plain fp32 layernorm (final) ----------------
__global__ __launch_bounds__(256) void ln_kernel(const float* __restrict__ in,
                                                 float* __restrict__ out,
                                                 const float* __restrict__ g,
                                                 const float* __restrict__ be, int W) {
    __shared__ float red[8];
    const int row = blockIdx.x;
    const float* xr = in + (size_t)row * W;
    float s = 0.f, s2 = 0.f;
    for (int i = threadIdx.x; i < W; i += 256) { float v = xr[i]; s += v; s2 += v * v; }
    for (int off = 32; off; off >>= 1) { s += __shfl_xor(s, off); s2 += __shfl_xor(s2, off); }
    int w = threadIdx.x >> 6;
    if ((threadIdx.x & 63) == 0) { red[w] = s; red[4 + w] = s2; }
    __syncthreads();
    s = red[0] + red[1] + red[2] + red[3];
    s2 = red[4] + red[5] + red[6] + red[7];
    float mean = s / W;
    float var = s2 / W - mean * mean;
    float rs = rsqrtf(var + 1e-5f);
    float* yr = out + (size_t)row * W;
    for (int i = threadIdx.x; i < W; i += 256)
        yr[i] = (xr[i] - mean) * rs * g[i] + be[i];
}

// ---------------- 2b. layernorm -> split-bf16 (hi,lo,hi interleave along K) ----------------
__global__ __launch_bounds__(256) void ln_split_kernel(const float* __restrict__ in, int Win,
                                                       u16* __restrict__ out, int Wp,
                                                       const float* __restrict__ g,
                                                       const float* __restrict__ be) {
    __shared__ float red[8];
    const int row = blockIdx.x;
    const float* xr = in + (size_t)row * Win;
    float s = 0.f, s2 = 0.f;
    for (int i = threadIdx.x; i < Win; i += 256) { float v = xr[i]; s += v; s2 += v * v; }
    for (int off = 32; off; off >>= 1) { s += __shfl_xor(s, off); s2 += __shfl_xor(s2, off); }
    int w = threadIdx.x >> 6;
    if ((threadIdx.x & 63) == 0) { red[w] = s; red[4 + w] = s2; }
    __syncthreads();
    s = red[0] + red[1] + red[2] + red[3];
    s2 = red[4] + red[5] + red[6] + red[7];
    float mean = s / Win;
    float var = s2 / Win - mean * mean;
    float rs = rsqrtf(var + 1e-5f);
    u16* yr = out + (size_t)row * 3 * Wp;
    for (int i = threadIdx.x; i < (Wp >> 2); i += 256) {
        int k = i << 2;
        u16 u[12];
#pragma unroll
        for (int j = 0; j < 4; ++j) {
            float v = (k + j < Win) ? (xr[k + j] - mean) * rs * g[k + j] + be[k + j] : 0.f;
            u16 hi = f2bf(v); float rem = v - bf2f(hi); u16 lo = f2bf(rem);
            u[j * 3] = hi; u[j * 3 + 1] = lo; u[j * 3 + 2] = hi;     // A pattern
        }
        uint2* dst = (uint2*)(yr + 3 * k);
        dst[0] = {(u32)u[0] | ((u32)u[1] << 16), (u32)u[2] | ((u32)u[3] << 16)};
        dst[1] = {(u32)u[4] | ((u32)u[5] << 16), (u32)u[6] | ((u32)u[7] << 16)};
        dst[2] = {(u32)u[8] | ((u32)u[9] << 16), (u32)u[10] | ((u32)u[11] << 16)};
    }
}

// ---- 3. weight convert: fp32 [K][ldw] slice -> bf16 W3T [Ncols][3Kp] (hi,hi,lo) ----
// grid = (Kp/32, Ncols/32)
__global__ __launch_bounds__(256) void cvtw_kernel(const float* __restrict__ W, int ldw,
                                                   u16* __restrict__ out,
                                                   int K, int Kp) {
    __shared__ float tile[32][33];
    int k0 = blockIdx.x * 32, n0 = blockIdx.y * 32;
    int tid = threadIdx.x;
    int col = tid & 31, r0 = tid >> 5;
#pragma unroll
    for (int p = 0; p < 4; ++p) {
        int k = k0 + r0 + p * 8;
        tile[r0 + p * 8][col] = (k < K) ? W[(size_t)k * ldw + n0 + col] : 0.f;
    }
    __syncthreads();
    int n = tid >> 3, kc = (tid & 7) << 2;
    u16 u[12];
#pragma unroll
    for (int i = 0; i < 4; ++i) {
        float v = tile[kc + i][n];
        u16 hi = f2bf(v); float rem = v - bf2f(hi); u16 lo = f2bf(rem);
        u[i * 3] = hi; u[i * 3 + 1] = hi; u[i * 3 + 2] = lo;          // B pattern
    }
    u16* dst = out + (size_t)(n0 + n) * 3 * Kp + 3 * (k0 + kc);
    uint2* q = (uint2*)dst;
    q[0] = {(u32)u[0] | ((u32)u[1] << 16), (u32)u[2] | ((u32)u[3] << 16)};
    q[1] = {(u32)u[4] | ((u32)u[5] << 16), (u32)u[6] | ((u32)u[7] << 16)};
    q[2] = {(u32)u[8] | ((u32)u[9] << 16), (u32)u[10] | ((u32)u[11] << 16)};
}

// ---------------- 4. bf16 MFMA GEMM, double-buffered prefetch ----------------
// C[M][N] = A[M][Kd] * Bw[N][Kd]^T
// MODE 0: fp32 out (+bias?,+add1,+add2,clamp)  MODE 1: bf16 out  MODE 2: relu+split3 out
template<int TM, int TN, int MODE>
__global__ __launch_bounds__(256) void gemm_bf16(
    const u16* __restrict__ A, int lda,
    const u16* __restrict__ Bw, int ldb,
    const float* __restrict__ bias,
    const float* add1,
    const float* add2,
    void* Cout, int N, int Kd, int do_clamp)
{
    constexpr int ISS_A = TM * 8 / 256;
    constexpr int ISS_B = TN * 8 / 256;
    constexpr int WM = TM / 2, WN = TN / 2;
    constexpr int FM = WM / 16, FN = WN / 16;
    __shared__ u16 As[2][TM * 64];
    __shared__ u16 Bs[2][TN * 64];
    const int tid = threadIdx.x;
    const int lane = tid & 63, wid = tid >> 6;
    const int wm = wid >> 1, wn = wid & 1;
    const int lr = lane & 15, lg = lane >> 4;
    const int m0 = blockIdx.y * TM, n0 = blockIdx.x * TN;
    const f32x4 fzero = {0.f, 0.f, 0.f, 0.f};
    f32x4 acc[FM][FN];
#pragma unroll
    for (int i = 0; i < FM; ++i)
#pragma unroll
        for (int j = 0; j < FN; ++j) acc[i][j] = fzero;

    const int nk = Kd >> 6;
    auto STAGE = [&](int buf, int kt) {
        const int k0 = kt << 6;
#pragma unroll
        for (int i = 0; i < ISS_A; ++i) {
            int slot = i * 256 + tid;
            int row = slot >> 3, c = slot & 7;
            gload16(A + (size_t)(m0 + row) * lda + k0 + ((c ^ (row & 7)) << 3),
                    &As[buf][slot << 3]);
        }
#pragma unroll
        for (int i = 0; i < ISS_B; ++i) {
            int slot = i * 256 + tid;
            int row = slot >> 3, c = slot & 7;
            gload16(Bw + (size_t)(n0 + row) * ldb + k0 + ((c ^ (row & 7)) << 3),
                    &Bs[buf][slot << 3]);
        }
    };

    STAGE(0, 0);
    __syncthreads();                      // drains vmcnt(0) + barrier
    int buf = 0;
    for (int kt = 0; kt < nk; ++kt) {
        if (kt + 1 < nk) STAGE(buf ^ 1, kt + 1);   // issue next-tile loads first
#pragma unroll
        for (int ks = 0; ks < 2; ++ks) {
            short8 av[FM], bv[FN];
#pragma unroll
            for (int mf = 0; mf < FM; ++mf) {
                int row = wm * WM + mf * 16 + lr;
                int c = ks * 4 + lg;
                av[mf] = *(const short8*)&As[buf][((row << 3) + (c ^ (row & 7))) << 3];
            }
#pragma unroll
            for (int nf = 0; nf < FN; ++nf) {
                int row = wn * WN + nf * 16 + lr;
                int c = ks * 4 + lg;
                bv[nf] = *(const short8*)&Bs[buf][((row << 3) + (c ^ (row & 7))) << 3];
            }
#pragma unroll
            for (int mf = 0; mf < FM; ++mf)
#pragma unroll
                for (int nf = 0; nf < FN; ++nf)
                    acc[mf][nf] = MFMA(av[mf], bv[nf], acc[mf][nf]);
        }
        __syncthreads();                  // drain prefetch + protect buf swap
        buf ^= 1;
    }
    // epilogue
#pragma unroll
    for (int mf = 0; mf < FM; ++mf)
#pragma unroll
        for (int nf = 0; nf < FN; ++nf)
#pragma unroll
            for (int r = 0; r < 4; ++r) {
                int grow = m0 + wm * WM + mf * 16 + lg * 4 + r;
                int gcol = n0 + wn * WN + nf * 16 + lr;
                float v = acc[mf][nf][r];
                if (bias) v += bias[gcol];
                if constexpr (MODE == 0) {
                    size_t off = (size_t)grow * N + gcol;
                    if (add1) v += add1[off];
                    if (add2) v += add2[off];
                    if (do_clamp) v = fminf(fmaxf(v, -60000.f), 60000.f);
                    ((float*)Cout)[off] = v;
                } else if constexpr (MODE == 1) {
                    ((u16*)Cout)[(size_t)grow * N + gcol] = f2bf(v);
                } else {
                    v = fmaxf(v, 0.f);
                    u16 hi = f2bf(v); float rem = v - bf2f(hi); u16 lo = f2bf(rem);
                    u16* p = (u16*)Cout + (size_t)grow * 3 * N + 3 * gcol;
                    p[0] = hi; p[1] = lo; p[2] = hi;                 // A pattern
                }
            }
}

// ---------------- 5. FSMN depthwise conv on v (bf16 in, fp32 out) ----------------
__global__ __launch_bounds__(256) void fsmn_kernel(const u16* __restrict__ qkv,
                                                   const float* __restrict__ mask,
                                                   const float* __restrict__ w,
                                                   float* __restrict__ mem) {
    int g = blockIdx.x * 256 + threadIdx.x;     // over BT*64
    int bt = g >> 6;
    int d0 = (g & 63) << 3;
    int t = bt & (Tt - 1), b = bt >> 10;
    float acc[8] = {0.f, 0.f, 0.f, 0.f, 0.f, 0.f, 0.f, 0.f};
#pragma unroll
    for (int j = 0; j < 11; ++j) {
        int tt = t + j - 5;
        if (tt < 0 || tt >= Tt) continue;
        float mk = mask[b * Tt + tt];
        union { uint4 q; u16 s[8]; } U;
        U.q = *(const uint4*)(qkv + (size_t)(b * Tt + tt) * QKV_N + 1024 + d0);
#pragma unroll
        for (int e = 0; e < 8; ++e)
            acc[e] += bf2f(U.s[e]) * mk * w[(d0 + e) * 11 + j];
    }
    float mk0 = mask[b * Tt + t];
    union { uint4 q; u16 s[8]; } U0;
    U0.q = *(const uint4*)(qkv + (size_t)bt * QKV_N + 1024 + d0);
    float out[8];
#pragma unroll
    for (int e = 0; e < 8; ++e) {
        float vm = bf2f(U0.s[e]) * mk0;
        out[e] = (acc[e] + vm) * mk0;
    }
    float4 o0 = {out[0], out[1], out[2], out[3]};
    float4 o1 = {out[4], out[5], out[6], out[7]};
    float* mp = mem + (size_t)bt * Dd + d0;
    *(float4*)mp = o0; *(float4*)(mp + 4) = o1;
}

// ---------------- 6. V transpose: QKVb v-part -> Vt[bh][d=128][t=1024] ----------------
__global__ __launch_bounds__(256) void vtrans_kernel(const u16* __restrict__ qkv,
                                                     u16* __restrict__ vt) {
    __shared__ u16 tile[32][33];
    int bh = blockIdx.z, b = bh >> 2, h = bh & 3;
    int t0 = blockIdx.x * 32, d0 = blockIdx.y * 32;
    int tid = threadIdx.x;
    int col = tid & 31, r0 = tid >> 5;
#pragma unroll
    for (int p = 0; p < 4; ++p) {
        int tl = r0 + p * 8;
        tile[tl][col] = qkv[(size_t)(b * Tt + t0 + tl) * QKV_N + 1024 + h * 128 + d0 + col];
    }
    __syncthreads();
    int dl = tid >> 3, tc = (tid & 7) << 2;
    u16 u[4];
#pragma unroll
    for (int i = 0; i < 4; ++i) u[i] = tile[tc + i][dl];
    uint2 val = {(u32)u[0] | ((u32)u[1] << 16), (u32)u[2] | ((u32)u[3] << 16)};
    *(uint2*)(vt + (size_t)(bh * 128 + d0 + dl) * Tt + t0 + tc) = val;
}

// ---------------- 7. fused flash attention (bf16 MFMA), K/V double-buffered ----------------
__global__ __launch_bounds__(256) void attn_kernel(const u16* __restrict__ qkv,
                                                   const u16* __restrict__ vt,
                                                   const float* __restrict__ mask,
                                                   u16* __restrict__ ctx3) {
    __shared__ u16 Qs[64 * 128];        // 64 q rows x 256B
    __shared__ u16 Ks[2][64 * 128];     // double-buffered K tiles
    __shared__ u16 Vs[2][128 * 64];     // double-buffered V tiles (transposed)
    __shared__ u16 Ps[4][16 * 72];      // per-wave P, padded rows
    __shared__ float mLds[Tt];
    const int tid = threadIdx.x;
    const int lane = tid & 63, wid = tid >> 6;
    const int lr = lane & 15, lg = lane >> 4;
    // XCD-chunked block mapping: same (b,h) stays on one XCD
    int L = blockIdx.x;
    int xcd = L & 7, slot = L >> 3;
    int bh = (slot >= 16) ? xcd + 8 : xcd;
    int qt = slot & 15;
    int b = bh >> 2, h = bh & 3;
    const size_t base = (size_t)b * Tt * QKV_N;
    const int q0 = qt * 64;
    const float c2 = 0.08838834764831845f * 1.44269504088896340736f;  // scale*log2(e)

    auto STAGE_KV = [&](int buf, int kvt) {
        int t0 = kvt * 64;
#pragma unroll
        for (int i = 0; i < 4; ++i) {    // K: 64 rows x 16 chunks
            int s = i * 256 + tid;
            int row = s >> 4, c = s & 15;
            gload16(qkv + base + (size_t)(t0 + row) * QKV_N + 512 + h * 128 + ((c ^ (row & 7)) << 3),
                    &Ks[buf][s << 3]);
        }
#pragma unroll
        for (int i = 0; i < 4; ++i) {    // V: 128 d-rows x 8 chunks
            int s = i * 256 + tid;
            int row = s >> 3, c = s & 7;
            gload16(vt + (size_t)(bh * 128 + row) * Tt + t0 + ((c ^ (row & 7)) << 3),
                    &Vs[buf][s << 3]);
        }
    };

#pragma unroll
    for (int i = 0; i < 4; ++i) {        // Q: 64 rows x 16 chunks
        int s = i * 256 + tid;
        int row = s >> 4, c = s & 15;
        gload16(qkv + base + (size_t)(q0 + row) * QKV_N + h * 128 + ((c ^ (row & 7)) << 3),
                &Qs[s << 3]);
    }
    for (int i = tid; i < Tt; i += 256) mLds[i] = mask[b * Tt + i];
    STAGE_KV(0, 0);

    const f32x4 fzero = {0.f, 0.f, 0.f, 0.f};
    f32x4 o[8];
#pragma unroll
    for (int i = 0; i < 8; ++i) o[i] = fzero;
    float mrun[4] = {-3e38f, -3e38f, -3e38f, -3e38f};
    float lrun[4] = {0.f, 0.f, 0.f, 0.f};

    __syncthreads();                     // drains Q + tile0 staging
    int buf = 0;
    for (int kvt = 0; kvt < 16; ++kvt) {
        int t0 = kvt * 64;
        if (kvt + 1 < 16) STAGE_KV(buf ^ 1, kvt + 1);   // prefetch next tile

        // S = Q K^T : 16 q rows (this wave) x 64 kv
        f32x4 s4[4] = {fzero, fzero, fzero, fzero};
#pragma unroll
        for (int ks = 0; ks < 4; ++ks) {
            int qrow = wid * 16 + lr;
            int c = ks * 4 + lg;
            short8 aq = *(const short8*)&Qs[((qrow << 4) + (c ^ (qrow & 7))) << 3];
#pragma unroll
            for (int nf = 0; nf < 4; ++nf) {
                int krow = nf * 16 + lr;
                short8 bk = *(const short8*)&Ks[buf][((krow << 4) + (c ^ (krow & 7))) << 3];
                s4[nf] = MFMA(aq, bk, s4[nf]);
            }
        }
        // online softmax (rows = lg*4+r of this wave's 16)
        float tmax[4] = {-3e38f, -3e38f, -3e38f, -3e38f};
#pragma unroll
        for (int nf = 0; nf < 4; ++nf) {
            float mv = mLds[t0 + nf * 16 + lr];
#pragma unroll
            for (int r = 0; r < 4; ++r) {
                float sv = s4[nf][r] + ((mv == 0.f) ? -1e30f : 0.f);
                s4[nf][r] = sv;
                tmax[r] = fmaxf(tmax[r], sv);
            }
        }
#pragma unroll
        for (int off = 8; off >= 1; off >>= 1)
#pragma unroll
            for (int r = 0; r < 4; ++r) tmax[r] = fmaxf(tmax[r], __shfl_xor(tmax[r], off));
        float rs[4];
#pragma unroll
        for (int r = 0; r < 4; ++r) {
            float mnew = fmaxf(mrun[r], tmax[r]);
            float ex = exp2f((mrun[r] - mnew) * c2);
            mrun[r] = mnew; lrun[r] *= ex; rs[r] = ex;
        }
#pragma unroll
        for (int nf = 0; nf < 8; ++nf)
#pragma unroll
            for (int r = 0; r < 4; ++r) o[nf][r] *= rs[r];
        float psum[4] = {0.f, 0.f, 0.f, 0.f};
#pragma unroll
        for (int nf = 0; nf < 4; ++nf)
#pragma unroll
            for (int r = 0; r < 4; ++r) {
                float pv = exp2f((s4[nf][r] - mrun[r]) * c2);
                psum[r] += pv;
                Ps[wid][(lg * 4 + r) * 72 + nf * 16 + lr] = f2bf(pv);
            }
#pragma unroll
        for (int off = 8; off >= 1; off >>= 1)
#pragma unroll
            for (int r = 0; r < 4; ++r) psum[r] += __shfl_xor(psum[r], off);
#pragma unroll
        for (int r = 0; r < 4; ++r) lrun[r] += psum[r];

        // O += P V   (P rows=q, V transposed in LDS)
#pragma unroll
        for (int ks2 = 0; ks2 < 2; ++ks2) {
            short8 pa = *(const short8*)&Ps[wid][lr * 72 + ks2 * 32 + lg * 8];
#pragma unroll
            for (int nf = 0; nf < 8; ++nf) {
                int vrow = nf * 16 + lr;
                int c = ks2 * 4 + lg;
                short8 vb = *(const short8*)&Vs[buf][((vrow << 3) + (c ^ (vrow & 7))) << 3];
                o[nf] = MFMA(pa, vb, o[nf]);
            }
        }
        __syncthreads();                 // drain prefetch + protect buf swap
        buf ^= 1;
    }
    // epilogue: normalize, write split-bf16 CTX3
    float inv[4];
#pragma unroll
    for (int r = 0; r < 4; ++r) inv[r] = 1.f / lrun[r];
#pragma unroll
    for (int nf = 0; nf < 8; ++nf)
#pragma unroll
        for (int r = 0; r < 4; ++r) {
            int grow = b * Tt + q0 + wid * 16 + lg * 4 + r;
            int gcol = h * 128 + nf * 16 + lr;
            float v = o[nf][r] * inv[r];
            u16 hi = f2bf(v); float rem = v - bf2f(hi); u16 lo = f2bf(rem);
            u16* p = ctx3 + (size_t)grow * 1536 + 3 * gcol;
            p[0] = hi; p[1] = lo; p[2] = hi;
        }
}

// ---------------- launch ----------------
extern "C" void kernel_launch(void* const* d_in, const int* in_sizes, int n_in,
                              void* d_out, int out_size, void* d_ws, size_t ws_size,
                              hipStream_t stream) {
    const float* x    = (const float*)d_in[0];
    const float* mask = (const float*)d_in[1];

    char* p = (char*)d_ws;
    float* X   = (float*)p; p += 9175040;            // BT x 560 fp32
    float* X2  = (float*)p; p += 8388608;            // BT x 512 fp32
    u16*   XN3 = (u16*)p;   p += 14155776;           // BT x 1728 bf16 (CTX3 aliases)
    u16*   QKVb= (u16*)p;   p += 12582912;           // BT x 1536 bf16
    float* MEM = (float*)p; p += 8388608;            // BT x 512 fp32
    u16*   Vt  = (u16*)p;   p += 4194304;            // 16 x 128 x 1024 bf16
    u16*   W3  = (u16*)p;   p += 6291456;            // weight scratch (serial reuse)
    u16*   W3b = W3 + 1024 * 1536;                   // second half (FFN w2 slice)
    u16*   FFH3 = QKVb;                              // [4096 x 3072] aliases QKVb+MEM+Vt exactly
    u16*   CTX3 = XN3;

    prep_kernel<<<(BT * DIN) / 256, 256, 0, stream>>>(x, X);

    for (int l = 0; l < Ll; ++l) {
        const float *ln1w, *ln1b, *qkvw, *qkvb, *outw, *outb, *fsmnw;
        const float *ln2w, *ln2b, *w1, *b1, *w2, *b2;
        if (l == 0) {
            ln1w = (const float*)d_in[2];  ln1b = (const float*)d_in[3];
            qkvw = (const float*)d_in[4];  qkvb = (const float*)d_in[5];
            outw = (const float*)d_in[6];  outb = (const float*)d_in[7];
            fsmnw = (const float*)d_in[8];
            ln2w = (const float*)d_in[9];  ln2b = (const float*)d_in[10];
            w1 = (const float*)d_in[11];   b1 = (const float*)d_in[12];
            w2 = (const float*)d_in[13];   b2 = (const float*)d_in[14];
        } else {
            int i = l - 1;
            ln1w = (const float*)d_in[15] + (size_t)i * Dd;
            ln1b = (const float*)d_in[16] + (size_t)i * Dd;
            qkvw = (const float*)d_in[17] + (size_t)i * Dd * QKV_N;
            qkvb = (const float*)d_in[18] + (size_t)i * QKV_N;
            outw = (const float*)d_in[19] + (size_t)i * Dd * Dd;
            outb = (const float*)d_in[20] + (size_t)i * Dd;
            fsmnw = (const float*)d_in[21] + (size_t)i * Dd * 11;
            ln2w = (const float*)d_in[22] + (size_t)i * Dd;
            ln2b = (const float*)d_in[23] + (size_t)i * Dd;
            w1 = (const float*)d_in[24] + (size_t)i * Dd * FFd;
            b1 = (const float*)d_in[25] + (size_t)i * FFd;
            w2 = (const float*)d_in[26] + (size_t)i * FFd * Dd;
            b2 = (const float*)d_in[27] + (size_t)i * Dd;
        }
        const int Win = (l == 0) ? DIN : Dd;          // 560 / 512
        const int Kp  = (l == 0) ? 576 : 512;         // padded K
        const int ld3 = 3 * Kp;                       // 1728 / 1536

        // qkv weights -> W3 ; LN1 -> XN3 ; QKV GEMM -> QKVb (bf16)
        cvtw_kernel<<<dim3(Kp / 32, QKV_N / 32), 256, 0, stream>>>(qkvw, QKV_N, W3, Win, Kp);
        ln_split_kernel<<<BT, 256, 0, stream>>>(X, Win, XN3, Kp, ln1w, ln1b);
        gemm_bf16<64, 128, 1><<<dim3(QKV_N / 128, BT / 64), 256, 0, stream>>>(
            XN3, ld3, W3, ld3, qkvb, nullptr, nullptr, QKVb, QKV_N, ld3, 0);
        // out-proj weights can be converted now (W3 free)
        cvtw_kernel<<<dim3(16, 16), 256, 0, stream>>>(outw, Dd, W3, Dd, Dd);
        // FSMN memory branch + V transpose + attention
        fsmn_kernel<<<(BT * 64) / 256, 256, 0, stream>>>(QKVb, mask, fsmnw, MEM);
        vtrans_kernel<<<dim3(32, 4, 16), 256, 0, stream>>>(QKVb, Vt);
        attn_kernel<<<256, 256, 0, stream>>>(QKVb, Vt, mask, CTX3);
        // out-proj: X2 = CTX3 @ outw + outb + MEM (+X for l>0)
        gemm_bf16<64, 64, 0><<<dim3(Dd / 64, BT / 64), 256, 0, stream>>>(
            CTX3, 1536, W3, 1536, outb, MEM, (l == 0) ? nullptr : X, X2, Dd, 1536, 0);
        // LN2 -> XN3 (overwrites CTX3, now dead)
        ln_split_kernel<<<BT, 256, 0, stream>>>(X2, Dd, XN3, Dd, ln2w, ln2b);
        // FFN, N-split into two hidden halves of 1024; FFN2 chains K=3072 each.
        // W3 holds w1-half [1024][3*512] and w2-half [512][3*1024] simultaneously.
        for (int hh = 0; hh < 2; ++hh) {
            // w1 cols hh*1024.. ; w2 rows hh*1024..
            cvtw_kernel<<<dim3(16, 32), 256, 0, stream>>>(w1 + hh * 1024, FFd, W3, Dd, Dd);
            cvtw_kernel<<<dim3(32, 16), 256, 0, stream>>>(w2 + (size_t)hh * 1024 * Dd, Dd,
                                                          W3b, 1024, 1024);
            // FFN1 half: FFH3[4096][3*1024] = relu(XN3 @ w1h + b1h), split3
            gemm_bf16<64, 128, 2><<<dim3(1024 / 128, BT / 64), 256, 0, stream>>>(
                XN3, 1536, W3, 1536, b1 + hh * 1024, nullptr, nullptr, FFH3, 1024, 1536, 0);
            // FFN2 half: X = (hh==0 ? X2 + b2 : X) + FFH3 @ w2h ; clamp on last
            if (hh == 0)
                gemm_bf16<64, 64, 0><<<dim3(Dd / 64, BT / 64), 256, 0, stream>>>(
                    FFH3, 3072, W3b, 3072, b2, X2, nullptr, X, Dd, 3072, 0);
            else
                gemm_bf16<64, 64, 0><<<dim3(Dd / 64, BT / 64), 256, 0, stream>>>(
                    FFH3, 3072, W3b, 3072, nullptr, X, nullptr, X, Dd, 3072, 1);
        }
    }

    // final layernorm -> d_out
    ln_kernel<<<BT, 256, 0, stream>>>(X, (float*)d_out,
                                      (const float*)d_in[28], (const float*)d_in[29], Dd);
}

// Round 12
// 2134.242 us; speedup vs baseline: 1.0260x; 1.0260x over previous
//
#include <hip/hip_runtime.h>
#include <cmath>

// ---------------- problem constants ----------------
#define Bb 4
#define Tt 1024
#define DIN 560
#define Dd 512
#define FFd 2048
#define Ll 6
#define BT (Bb * Tt)          // 4096 rows
#define QKV_N (3 * Dd)        // 1536

typedef unsigned short u16;
typedef unsigned int u32;
typedef __attribute__((ext_vector_type(8))) short short8;
typedef __attribute__((ext_vector_type(4))) float f32x4;

static __device__ __forceinline__ u16 f2bf(float f) {          // RNE fp32->bf16
    u32 u = __float_as_uint(f);
    return (u16)((u + 0x7fffu + ((u >> 16) & 1u)) >> 16);
}
static __device__ __forceinline__ float bf2f(u16 h) { return __uint_as_float((u32)h << 16); }

static __device__ __forceinline__ f32x4 MFMA(short8 a, short8 b, f32x4 c) {
    return __builtin_amdgcn_mfma_f32_16x16x32_bf16(a, b, c, 0, 0, 0);
}

static __device__ __forceinline__ void gload16(const u16* g, u16* l) {
    __builtin_amdgcn_global_load_lds(
        (const __attribute__((address_space(1))) void*)g,
        (__attribute__((address_space(3))) void*)l, 16, 0, 0);
}

template<int N> static __device__ __forceinline__ void vmwait() {
    asm volatile("s_waitcnt vmcnt(%0)" :: "n"(N) : "memory");
}

// ---------------- 1. preprocess: x*sqrt(D) + pos_encode ----------------
__global__ __launch_bounds__(256) void prep_kernel(const float* __restrict__ x,
                                                   float* __restrict__ out) {
    int idx = blockIdx.x * 256 + threadIdx.x;       // over BT*DIN, exact
    int d = idx % DIN;
    int bt = idx / DIN;
    int t = bt & (Tt - 1);
    const float log_inc = 9.210340371976184f / 279.0f;   // ln(10000)/(half-1)
    int i = (d < 280) ? d : d - 280;
    float ang = (float)(t + 1) * expf(-(float)i * log_inc);
    float pe = (d < 280) ? sinf(ang) : cosf(ang);
    out[idx] = x[idx] * 22.627416997969522f + pe;        // sqrt(512)
}

// ---------------- 2a. plain fp32 layernorm (final) ----------------
__global__ __launch_bounds__(256) void ln_kernel(const float* __restrict__ in,
                                                 float* __restrict__ out,
                                                 const float* __restrict__ g,
                                                 const float* __restrict__ be, int W) {
    __shared__ float red[8];
    const int row = blockIdx.x;
    const float* xr = in + (size_t)row * W;
    float s = 0.f, s2 = 0.f;
    for (int i = threadIdx.x; i < W; i += 256) { float v = xr[i]; s += v; s2 += v * v; }
    for (int off = 32; off; off >>= 1) { s += __shfl_xor(s, off); s2 += __shfl_xor(s2, off); }
    int w = threadIdx.x >> 6;
    if ((threadIdx.x & 63) == 0) { red[w] = s; red[4 + w] = s2; }
    __syncthreads();
    s = red[0] + red[1] + red[2] + red[3];
    s2 = red[4] + red[5] + red[6] + red[7];
    float mean = s / W;
    float var = s2 / W - mean * mean;
    float rs = rsqrtf(var + 1e-5f);
    float* yr = out + (size_t)row * W;
    for (int i = threadIdx.x; i < W; i += 256)
        yr[i] = (xr[i] - mean) * rs * g[i] + be[i];
}

// ---------------- 2b. layernorm -> split-bf16 (hi,lo,hi interleave along K) ----------------
__global__ __launch_bounds__(256) void ln_split_kernel(const float* __restrict__ in, int Win,
                                                       u16* __restrict__ out, int Wp,
                                                       const float* __restrict__ g,
                                                       const float* __restrict__ be) {
    __shared__ float red[8];
    const int row = blockIdx.x;
    const float* xr = in + (size_t)row * Win;
    float s = 0.f, s2 = 0.f;
    for (int i = threadIdx.x; i < Win; i += 256) { float v = xr[i]; s += v; s2 += v * v; }
    for (int off = 32; off; off >>= 1) { s += __shfl_xor(s, off); s2 += __shfl_xor(s2, off); }
    int w = threadIdx.x >> 6;
    if ((threadIdx.x & 63) == 0) { red[w] = s; red[4 + w] = s2; }
    __syncthreads();
    s = red[0] + red[1] + red[2] + red[3];
    s2 = red[4] + red[5] + red[6] + red[7];
    float mean = s / Win;
    float var = s2 / Win - mean * mean;
    float rs = rsqrtf(var + 1e-5f);
    u16* yr = out + (size_t)row * 3 * Wp;
    for (int i = threadIdx.x; i < (Wp >> 2); i += 256) {
        int k = i << 2;
        u16 u[12];
#pragma unroll
        for (int j = 0; j < 4; ++j) {
            float v = (k + j < Win) ? (xr[k + j] - mean) * rs * g[k + j] + be[k + j] : 0.f;
            u16 hi = f2bf(v); float rem = v - bf2f(hi); u16 lo = f2bf(rem);
            u[j * 3] = hi; u[j * 3 + 1] = lo; u[j * 3 + 2] = hi;     // A pattern
        }
        uint2* dst = (uint2*)(yr + 3 * k);
        dst[0] = {(u32)u[0] | ((u32)u[1] << 16), (u32)u[2] | ((u32)u[3] << 16)};
        dst[1] = {(u32)u[4] | ((u32)u[5] << 16), (u32)u[6] | ((u32)u[7] << 16)};
        dst[2] = {(u32)u[8] | ((u32)u[9] << 16), (u32)u[10] | ((u32)u[11] << 16)};
    }
}

// ---- 3. weight convert: fp32 [K][ldw] slice -> bf16 W3T [Ncols][3Kp] (hi,hi,lo) ----
// grid = (Kp/32, Ncols/32)
__global__ __launch_bounds__(256) void cvtw_kernel(const float* __restrict__ W, int ldw,
                                                   u16* __restrict__ out,
                                                   int K, int Kp) {
    __shared__ float tile[32][33];
    int k0 = blockIdx.x * 32, n0 = blockIdx.y * 32;
    int tid = threadIdx.x;
    int col = tid & 31, r0 = tid >> 5;
#pragma unroll
    for (int p = 0; p < 4; ++p) {
        int k = k0 + r0 + p * 8;
        tile[r0 + p * 8][col] = (k < K) ? W[(size_t)k * ldw + n0 + col] : 0.f;
    }
    __syncthreads();
    int n = tid >> 3, kc = (tid & 7) << 2;
    u16 u[12];
#pragma unroll
    for (int i = 0; i < 4; ++i) {
        float v = tile[kc + i][n];
        u16 hi = f2bf(v); float rem = v - bf2f(hi); u16 lo = f2bf(rem);
        u[i * 3] = hi; u[i * 3 + 1] = hi; u[i * 3 + 2] = lo;          // B pattern
    }
    u16* dst = out + (size_t)(n0 + n) * 3 * Kp + 3 * (k0 + kc);
    uint2* q = (uint2*)dst;
    q[0] = {(u32)u[0] | ((u32)u[1] << 16), (u32)u[2] | ((u32)u[3] << 16)};
    q[1] = {(u32)u[4] | ((u32)u[5] << 16), (u32)u[6] | ((u32)u[7] << 16)};
    q[2] = {(u32)u[8] | ((u32)u[9] << 16), (u32)u[10] | ((u32)u[11] << 16)};
}

// ---------------- 4. bf16 MFMA GEMM, 3-buffer 2-ahead pipeline, counted vmcnt ----------------
// C[M][N] = A[M][Kd] * Bw[N][Kd]^T
// MODE 0: fp32 out (+bias?,+add1,+add2,clamp)  MODE 1: bf16 out  MODE 2: relu+split3 out
template<int TM, int TN, int MODE>
__global__ __launch_bounds__(256) void gemm_bf16(
    const u16* __restrict__ A, int lda,
    const u16* __restrict__ Bw, int ldb,
    const float* __restrict__ bias,
    const float* add1,
    const float* add2,
    void* Cout, int N, int Kd, int do_clamp)
{
    constexpr int ISS_A = TM * 8 / 256;
    constexpr int ISS_B = TN * 8 / 256;
    constexpr int LOADS = ISS_A + ISS_B;          // gload16s per thread per stage
    constexpr int WM = TM / 2, WN = TN / 2;
    constexpr int FM = WM / 16, FN = WN / 16;
    __shared__ u16 As[3][TM * 64];
    __shared__ u16 Bs[3][TN * 64];
    const int tid = threadIdx.x;
    const int lane = tid & 63, wid = tid >> 6;
    const int wm = wid >> 1, wn = wid & 1;
    const int lr = lane & 15, lg = lane >> 4;
    const int m0 = blockIdx.y * TM, n0 = blockIdx.x * TN;
    const f32x4 fzero = {0.f, 0.f, 0.f, 0.f};
    f32x4 acc[FM][FN];
#pragma unroll
    for (int i = 0; i < FM; ++i)
#pragma unroll
        for (int j = 0; j < FN; ++j) acc[i][j] = fzero;

    const int nk = Kd >> 6;
    auto STAGE = [&](int buf, int kt) {
        const int k0 = kt << 6;
#pragma unroll
        for (int i = 0; i < ISS_A; ++i) {
            int slot = i * 256 + tid;
            int row = slot >> 3, c = slot & 7;
            gload16(A + (size_t)(m0 + row) * lda + k0 + ((c ^ (row & 7)) << 3),
                    &As[buf][slot << 3]);
        }
#pragma unroll
        for (int i = 0; i < ISS_B; ++i) {
            int slot = i * 256 + tid;
            int row = slot >> 3, c = slot & 7;
            gload16(Bw + (size_t)(n0 + row) * ldb + k0 + ((c ^ (row & 7)) << 3),
                    &Bs[buf][slot << 3]);
        }
    };

    // prologue: 2 tiles in flight
    STAGE(0, 0);
    if (nk > 1) STAGE(1, 1);

    for (int kt = 0; kt < nk; ++kt) {
        const int buf = kt % 3;
        // (a) wait for tile kt (allow tile kt+1's LOADS to stay in flight)
        if (kt + 1 < nk) vmwait<LOADS>(); else vmwait<0>();
        // (b) all waves: tile kt ready AND compute kt-1 done everywhere
        __builtin_amdgcn_s_barrier();
        // (c) stage tile kt+2 into buf (kt+2)%3 — its old contents (tile kt-1) are dead
        if (kt + 2 < nk) STAGE((kt + 2) % 3, kt + 2);
        // (d) compute tile kt
#pragma unroll
        for (int ks = 0; ks < 2; ++ks) {
            short8 av[FM], bv[FN];
#pragma unroll
            for (int mf = 0; mf < FM; ++mf) {
                int row = wm * WM + mf * 16 + lr;
                int c = ks * 4 + lg;
                av[mf] = *(const short8*)&As[buf][((row << 3) + (c ^ (row & 7))) << 3];
            }
#pragma unroll
            for (int nf = 0; nf < FN; ++nf) {
                int row = wn * WN + nf * 16 + lr;
                int c = ks * 4 + lg;
                bv[nf] = *(const short8*)&Bs[buf][((row << 3) + (c ^ (row & 7))) << 3];
            }
#pragma unroll
            for (int mf = 0; mf < FM; ++mf)
#pragma unroll
                for (int nf = 0; nf < FN; ++nf)
                    acc[mf][nf] = MFMA(av[mf], bv[nf], acc[mf][nf]);
        }
    }
    // epilogue
#pragma unroll
    for (int mf = 0; mf < FM; ++mf)
#pragma unroll
        for (int nf = 0; nf < FN; ++nf)
#pragma unroll
            for (int r = 0; r < 4; ++r) {
                int grow = m0 + wm * WM + mf * 16 + lg * 4 + r;
                int gcol = n0 + wn * WN + nf * 16 + lr;
                float v = acc[mf][nf][r];
                if (bias) v += bias[gcol];
                if constexpr (MODE == 0) {
                    size_t off = (size_t)grow * N + gcol;
                    if (add1) v += add1[off];
                    if (add2) v += add2[off];
                    if (do_clamp) v = fminf(fmaxf(v, -60000.f), 60000.f);
                    ((float*)Cout)[off] = v;
                } else if constexpr (MODE == 1) {
                    ((u16*)Cout)[(size_t)grow * N + gcol] = f2bf(v);
                } else {
                    v = fmaxf(v, 0.f);
                    u16 hi = f2bf(v); float rem = v - bf2f(hi); u16 lo = f2bf(rem);
                    u16* p = (u16*)Cout + (size_t)grow * 3 * N + 3 * gcol;
                    p[0] = hi; p[1] = lo; p[2] = hi;                 // A pattern
                }
            }
}

// ---------------- 5. FSMN depthwise conv on v (bf16 in, fp32 out), w staged in LDS ----------------
__global__ __launch_bounds__(256) void fsmn_kernel(const u16* __restrict__ qkv,
                                                   const float* __restrict__ mask,
                                                   const float* __restrict__ w,
                                                   float* __restrict__ mem) {
    __shared__ float wl[11][516];       // [j][d], rows 2064B (16B-aligned), d0*4 = 32B stride
    int tid = threadIdx.x;
    for (int i = tid; i < Dd * 11; i += 256)       // coalesced global read, transpose to LDS
        wl[i % 11][i / 11] = w[i];
    __syncthreads();

    int g = blockIdx.x * 256 + tid;     // over BT*64
    int bt = g >> 6;
    int d0 = (g & 63) << 3;
    int t = bt & (Tt - 1), b = bt >> 10;
    float acc[8] = {0.f, 0.f, 0.f, 0.f, 0.f, 0.f, 0.f, 0.f};
#pragma unroll
    for (int j = 0; j < 11; ++j) {
        int tt = t + j - 5;
        if (tt < 0 || tt >= Tt) continue;
        float mk = mask[b * Tt + tt];
        union { uint4 q; u16 s[8]; } U;
        U.q = *(const uint4*)(qkv + (size_t)(b * Tt + tt) * QKV_N + 1024 + d0);
        float4 w0 = *(const float4*)&wl[j][d0];
        float4 w1 = *(const float4*)&wl[j][d0 + 4];
        acc[0] += bf2f(U.s[0]) * mk * w0.x; acc[1] += bf2f(U.s[1]) * mk * w0.y;
        acc[2] += bf2f(U.s[2]) * mk * w0.z; acc[3] += bf2f(U.s[3]) * mk * w0.w;
        acc[4] += bf2f(U.s[4]) * mk * w1.x; acc[5] += bf2f(U.s[5]) * mk * w1.y;
        acc[6] += bf2f(U.s[6]) * mk * w1.z; acc[7] += bf2f(U.s[7]) * mk * w1.w;
    }
    float mk0 = mask[b * Tt + t];
    union { uint4 q; u16 s[8]; } U0;
    U0.q = *(const uint4*)(qkv + (size_t)bt * QKV_N + 1024 + d0);
    float out[8];
#pragma unroll
    for (int e = 0; e < 8; ++e) {
        float vm = bf2f(U0.s[e]) * mk0;
        out[e] = (acc[e] + vm) * mk0;
    }
    float4 o0 = {out[0], out[1], out[2], out[3]};
    float4 o1 = {out[4], out[5], out[6], out[7]};
    float* mp = mem + (size_t)bt * Dd + d0;
    *(float4*)mp = o0; *(float4*)(mp + 4) = o1;
}

// ---------------- 6. V transpose: QKVb v-part -> Vt[bh][d=128][t=1024] ----------------
__global__ __launch_bounds__(256) void vtrans_kernel(const u16* __restrict__ qkv,
                                                     u16* __restrict__ vt) {
    __shared__ u16 tile[32][33];
    int bh = blockIdx.z, b = bh >> 2, h = bh & 3;
    int t0 = blockIdx.x * 32, d0 = blockIdx.y * 32;
    int tid = threadIdx.x;
    int col = tid & 31, r0 = tid >> 5;
#pragma unroll
    for (int p = 0; p < 4; ++p) {
        int tl = r0 + p * 8;
        tile[tl][col] = qkv[(size_t)(b * Tt + t0 + tl) * QKV_N + 1024 + h * 128 + d0 + col];
    }
    __syncthreads();
    int dl = tid >> 3, tc = (tid & 7) << 2;
    u16 u[4];
#pragma unroll
    for (int i = 0; i < 4; ++i) u[i] = tile[tc + i][dl];
    uint2 val = {(u32)u[0] | ((u32)u[1] << 16), (u32)u[2] | ((u32)u[3] << 16)};
    *(uint2*)(vt + (size_t)(bh * 128 + d0 + dl) * Tt + t0 + tc) = val;
}

// ---------------- 7. fused flash attention (bf16 MFMA), K/V double-buffered ----------------
__global__ __launch_bounds__(256) void attn_kernel(const u16* __restrict__ qkv,
                                                   const u16* __restrict__ vt,
                                                   const float* __restrict__ mask,
                                                   u16* __restrict__ ctx3) {
    __shared__ u16 Qs[64 * 128];        // 64 q rows x 256B
    __shared__ u16 Ks[2][64 * 128];     // double-buffered K tiles
    __shared__ u16 Vs[2][128 * 64];     // double-buffered V tiles (transposed)
    __shared__ u16 Ps[4][16 * 72];      // per-wave P, padded rows
    __shared__ float mLds[Tt];
    const int tid = threadIdx.x;
    const int lane = tid & 63, wid = tid >> 6;
    const int lr = lane & 15, lg = lane >> 4;
    // XCD-chunked block mapping: same (b,h) stays on one XCD
    int L = blockIdx.x;
    int xcd = L & 7, slot = L >> 3;
    int bh = (slot >= 16) ? xcd + 8 : xcd;
    int qt = slot & 15;
    int b = bh >> 2, h = bh & 3;
    const size_t base = (size_t)b * Tt * QKV_N;
    const int q0 = qt * 64;
    const float c2 = 0.08838834764831845f * 1.44269504088896340736f;  // scale*log2(e)

    auto STAGE_KV = [&](int buf, int kvt) {
        int t0 = kvt * 64;
#pragma unroll
        for (int i = 0; i < 4; ++i) {    // K: 64 rows x 16 chunks
            int s = i * 256 + tid;
            int row = s >> 4, c = s & 15;
            gload16(qkv + base + (size_t)(t0 + row) * QKV_N + 512 + h * 128 + ((c ^ (row & 7)) << 3),
                    &Ks[buf][s << 3]);
        }
#pragma unroll
        for (int i = 0; i < 4; ++i) {    // V: 128 d-rows x 8 chunks
            int s = i * 256 + tid;
            int row = s >> 3, c = s & 7;
            gload16(vt + (size_t)(bh * 128 + row) * Tt + t0 + ((c ^ (row & 7)) << 3),
                    &Vs[buf][s << 3]);
        }
    };

#pragma unroll
    for (int i = 0; i < 4; ++i) {        // Q: 64 rows x 16 chunks
        int s = i * 256 + tid;
        int row = s >> 4, c = s & 15;
        gload16(qkv + base + (size_t)(q0 + row) * QKV_N + h * 128 + ((c ^ (row & 7)) << 3),
                &Qs[s << 3]);
    }
    for (int i = tid; i < Tt; i += 256) mLds[i] = mask[b * Tt + i];
    STAGE_KV(0, 0);

    const f32x4 fzero = {0.f, 0.f, 0.f, 0.f};
    f32x4 o[8];
#pragma unroll
    for (int i = 0; i < 8; ++i) o[i] = fzero;
    float mrun[4] = {-3e38f, -3e38f, -3e38f, -3e38f};
    float lrun[4] = {0.f, 0.f, 0.f, 0.f};

    __syncthreads();                     // drains Q + tile0 staging
    int buf = 0;
    for (int kvt = 0; kvt < 16; ++kvt) {
        int t0 = kvt * 64;
        if (kvt + 1 < 16) STAGE_KV(buf ^ 1, kvt + 1);   // prefetch next tile

        // S = Q K^T : 16 q rows (this wave) x 64 kv
        f32x4 s4[4] = {fzero, fzero, fzero, fzero};
#pragma unroll
        for (int ks = 0; ks < 4; ++ks) {
            int qrow = wid * 16 + lr;
            int c = ks * 4 + lg;
            short8 aq = *(const short8*)&Qs[((qrow << 4) + (c ^ (qrow & 7))) << 3];
#pragma unroll
            for (int nf = 0; nf < 4; ++nf) {
                int krow = nf * 16 + lr;
                short8 bk = *(const short8*)&Ks[buf][((krow << 4) + (c ^ (krow & 7))) << 3];
                s4[nf] = MFMA(aq, bk, s4[nf]);
            }
        }
        // online softmax (rows = lg*4+r of this wave's 16)
        float tmax[4] = {-3e38f, -3e38f, -3e38f, -3e38f};
#pragma unroll
        for (int nf = 0; nf < 4; ++nf) {
            float mv = mLds[t0 + nf * 16 + lr];
#pragma unroll
            for (int r = 0; r < 4; ++r) {
                float sv = s4[nf][r] + ((mv == 0.f) ? -1e30f : 0.f);
                s4[nf][r] = sv;
                tmax[r] = fmaxf(tmax[r], sv);
            }
        }
#pragma unroll
        for (int off = 8; off >= 1; off >>= 1)
#pragma unroll
            for (int r = 0; r < 4; ++r) tmax[r] = fmaxf(tmax[r], __shfl_xor(tmax[r], off));
        float rs[4];
#pragma unroll
        for (int r = 0; r < 4; ++r) {
            float mnew = fmaxf(mrun[r], tmax[r]);
            float ex = exp2f((mrun[r] - mnew) * c2);
            mrun[r] = mnew; lrun[r] *= ex; rs[r] = ex;
        }
#pragma unroll
        for (int nf = 0; nf < 8; ++nf)
#pragma unroll
            for (int r = 0; r < 4; ++r) o[nf][r] *= rs[r];
        float psum[4] = {0.f, 0.f, 0.f, 0.f};
#pragma unroll
        for (int nf = 0; nf < 4; ++nf)
#pragma unroll
            for (int r = 0; r < 4; ++r) {
                float pv = exp2f((s4[nf][r] - mrun[r]) * c2);
                psum[r] += pv;
                Ps[wid][(lg * 4 + r) * 72 + nf * 16 + lr] = f2bf(pv);
            }
#pragma unroll
        for (int off = 8; off >= 1; off >>= 1)
#pragma unroll
            for (int r = 0; r < 4; ++r) psum[r] += __shfl_xor(psum[r], off);
#pragma unroll
        for (int r = 0; r < 4; ++r) lrun[r] += psum[r];

        // O += P V   (P rows=q, V transposed in LDS)
#pragma unroll
        for (int ks2 = 0; ks2 < 2; ++ks2) {
            short8 pa = *(const short8*)&Ps[wid][lr * 72 + ks2 * 32 + lg * 8];
#pragma unroll
            for (int nf = 0; nf < 8; ++nf) {
                int vrow = nf * 16 + lr;
                int c = ks2 * 4 + lg;
                short8 vb = *(const short8*)&Vs[buf][((vrow << 3) + (c ^ (vrow & 7))) << 3];
                o[nf] = MFMA(pa, vb, o[nf]);
            }
        }
        __syncthreads();                 // drain prefetch + protect buf swap
        buf ^= 1;
    }
    // epilogue: normalize, write split-bf16 CTX3
    float inv[4];
#pragma unroll
    for (int r = 0; r < 4; ++r) inv[r] = 1.f / lrun[r];
#pragma unroll
    for (int nf = 0; nf < 8; ++nf)
#pragma unroll
        for (int r = 0; r < 4; ++r) {
            int grow = b * Tt + q0 + wid * 16 + lg * 4 + r;
            int gcol = h * 128 + nf * 16 + lr;
            float v = o[nf][r] * inv[r];
            u16 hi = f2bf(v); float rem = v - bf2f(hi); u16 lo = f2bf(rem);
            u16* p = ctx3 + (size_t)grow * 1536 + 3 * gcol;
            p[0] = hi; p[1] = lo; p[2] = hi;
        }
}

// ---------------- launch ----------------
extern "C" void kernel_launch(void* const* d_in, const int* in_sizes, int n_in,
                              void* d_out, int out_size, void* d_ws, size_t ws_size,
                              hipStream_t stream) {
    const float* x    = (const float*)d_in[0];
    const float* mask = (const float*)d_in[1];

    char* p = (char*)d_ws;
    float* X   = (float*)p; p += 9175040;            // BT x 560 fp32
    float* X2  = (float*)p; p += 8388608;            // BT x 512 fp32
    u16*   XN3 = (u16*)p;   p += 14155776;           // BT x 1728 bf16 (CTX3 aliases)
    u16*   QKVb= (u16*)p;   p += 12582912;           // BT x 1536 bf16
    float* MEM = (float*)p; p += 8388608;            // BT x 512 fp32
    u16*   Vt  = (u16*)p;   p += 4194304;            // 16 x 128 x 1024 bf16
    u16*   W3  = (u16*)p;   p += 6291456;            // weight scratch (serial reuse)
    u16*   W3b = W3 + 1024 * 1536;                   // second half (FFN w2 slice)
    u16*   FFH3 = QKVb;                              // [4096 x 3072] aliases QKVb+MEM+Vt exactly
    u16*   CTX3 = XN3;

    prep_kernel<<<(BT * DIN) / 256, 256, 0, stream>>>(x, X);

    for (int l = 0; l < Ll; ++l) {
        const float *ln1w, *ln1b, *qkvw, *qkvb, *outw, *outb, *fsmnw;
        const float *ln2w, *ln2b, *w1, *b1, *w2, *b2;
        if (l == 0) {
            ln1w = (const float*)d_in[2];  ln1b = (const float*)d_in[3];
            qkvw = (const float*)d_in[4];  qkvb = (const float*)d_in[5];
            outw = (const float*)d_in[6];  outb = (const float*)d_in[7];
            fsmnw = (const float*)d_in[8];
            ln2w = (const float*)d_in[9];  ln2b = (const float*)d_in[10];
            w1 = (const float*)d_in[11];   b1 = (const float*)d_in[12];
            w2 = (const float*)d_in[13];   b2 = (const float*)d_in[14];
        } else {
            int i = l - 1;
            ln1w = (const float*)d_in[15] + (size_t)i * Dd;
            ln1b = (const float*)d_in[16] + (size_t)i * Dd;
            qkvw = (const float*)d_in[17] + (size_t)i * Dd * QKV_N;
            qkvb = (const float*)d_in[18] + (size_t)i * QKV_N;
            outw = (const float*)d_in[19] + (size_t)i * Dd * Dd;
            outb = (const float*)d_in[20] + (size_t)i * Dd;
            fsmnw = (const float*)d_in[21] + (size_t)i * Dd * 11;
            ln2w = (const float*)d_in[22] + (size_t)i * Dd;
            ln2b = (const float*)d_in[23] + (size_t)i * Dd;
            w1 = (const float*)d_in[24] + (size_t)i * Dd * FFd;
            b1 = (const float*)d_in[25] + (size_t)i * FFd;
            w2 = (const float*)d_in[26] + (size_t)i * FFd * Dd;
            b2 = (const float*)d_in[27] + (size_t)i * Dd;
        }
        const int Win = (l == 0) ? DIN : Dd;          // 560 / 512
        const int Kp  = (l == 0) ? 576 : 512;         // padded K
        const int ld3 = 3 * Kp;                       // 1728 / 1536

        // qkv weights -> W3 ; LN1 -> XN3 ; QKV GEMM -> QKVb (bf16)
        cvtw_kernel<<<dim3(Kp / 32, QKV_N / 32), 256, 0, stream>>>(qkvw, QKV_N, W3, Win, Kp);
        ln_split_kernel<<<BT, 256, 0, stream>>>(X, Win, XN3, Kp, ln1w, ln1b);
        gemm_bf16<64, 128, 1><<<dim3(QKV_N / 128, BT / 64), 256, 0, stream>>>(
            XN3, ld3, W3, ld3, qkvb, nullptr, nullptr, QKVb, QKV_N, ld3, 0);
        // out-proj weights can be converted now (W3 free)
        cvtw_kernel<<<dim3(16, 16), 256, 0, stream>>>(outw, Dd, W3, Dd, Dd);
        // FSMN memory branch + V transpose + attention
        fsmn_kernel<<<(BT * 64) / 256, 256, 0, stream>>>(QKVb, mask, fsmnw, MEM);
        vtrans_kernel<<<dim3(32, 4, 16), 256, 0, stream>>>(QKVb, Vt);
        attn_kernel<<<256, 256, 0, stream>>>(QKVb, Vt, mask, CTX3);
        // out-proj: X2 = CTX3 @ outw + outb + MEM (+X for l>0)
        gemm_bf16<64, 64, 0><<<dim3(Dd / 64, BT / 64), 256, 0, stream>>>(
            CTX3, 1536, W3, 1536, outb, MEM, (l == 0) ? nullptr : X, X2, Dd, 1536, 0);
        // LN2 -> XN3 (overwrites CTX3, now dead)
        ln_split_kernel<<<BT, 256, 0, stream>>>(X2, Dd, XN3, Dd, ln2w, ln2b);
        // FFN, N-split into two hidden halves of 1024; FFN2 chains K=3072 each.
        // W3 holds w1-half [1024][3*512] and w2-half [512][3*1024] simultaneously.
        for (int hh = 0; hh < 2; ++hh) {
            // w1 cols hh*1024.. ; w2 rows hh*1024..
            cvtw_kernel<<<dim3(16, 32), 256, 0, stream>>>(w1 + hh * 1024, FFd, W3, Dd, Dd);
            cvtw_kernel<<<dim3(32, 16), 256, 0, stream>>>(w2 + (size_t)hh * 1024 * Dd, Dd,
                                                          W3b, 1024, 1024);
            // FFN1 half: FFH3[4096][3*1024] = relu(XN3 @ w1h + b1h), split3
            gemm_bf16<64, 128, 2><<<dim3(1024 / 128, BT / 64), 256, 0, stream>>>(
                XN3, 1536, W3, 1536, b1 + hh * 1024, nullptr, nullptr, FFH3, 1024, 1536, 0);
            // FFN2 half: X = (hh==0 ? X2 + b2 : X) + FFH3 @ w2h ; clamp on last
            if (hh == 0)
                gemm_bf16<64, 64, 0><<<dim3(Dd / 64, BT / 64), 256, 0, stream>>>(
                    FFH3, 3072, W3b, 3072, b2, X2, nullptr, X, Dd, 3072, 0);
            else
                gemm_bf16<64, 64, 0><<<dim3(Dd / 64, BT / 64), 256, 0, stream>>>(
                    FFH3, 3072, W3b, 3072, nullptr, X, nullptr, X, Dd, 3072, 1);
        }
    }

    // final layernorm -> d_out
    ln_kernel<<<BT, 256, 0, stream>>>(X, (float*)d_out,
                                      (const float*)d_in[28], (const float*)d_in[29], Dd);
}